// Round 3
// baseline (953.039 us; speedup 1.0000x reference)
//
#include <hip/hip_runtime.h>
#include <stdint.h>

// Problem constants
#define N_    128
#define L_    128
#define V_    8000
#define IN_   64
#define H_    13
#define G_    52      // 4*H
#define E_    2048
#define TWOH  26
#define TOTW  742808  // total float elements across all 31 float inputs

typedef unsigned int   u32;
typedef unsigned short u16;

__device__ __forceinline__ float bfu(u16 u){
    u32 x = ((u32)u) << 16; float f; __builtin_memcpy(&f, &x, 4); return f;
}
// clamps are exact at saturation (sig(30)=1-9e-14, tanh(15)=1-2e-13)
__device__ __forceinline__ float sigf(float x){
    x = fminf(fmaxf(x, -30.f), 30.f);
    return 1.0f / (1.0f + __expf(-x));
}
__device__ __forceinline__ float tanh_(float x){
    x = fminf(fmaxf(x, -15.f), 15.f);
    float e = __expf(2.0f * x); return 1.0f - 2.0f / (e + 1.0f);
}

// ---------------------------------------------------------------------------
// K-1: dtype detection. fp32 arrays: low u16 of each dword is random mantissa
// bits -> bf16-exponent field uniform -> "wild". Genuine bf16 weights are
// essentially never wild. flag: 1 = fp32, 0 = bf16.
// ---------------------------------------------------------------------------
__global__ __launch_bounds__(64) void k_detect(const u16* __restrict__ emb_u16,
                                               int* __restrict__ flag){
    const int lane = threadIdx.x;
    int wild = 0;
    for (int i = lane; i < 1024; i += 64){
        u16 u = emb_u16[i];
        int e = (u >> 7) & 0xFF;
        int tame = (u == 0) || (u == 0x8000) || (e >= 0x60 && e <= 0x88);
        wild += !tame;
    }
    #pragma unroll
    for (int o = 32; o; o >>= 1) wild += __shfl_down(wild, o, 64);
    if (lane == 0) *flag = (wild > 200) ? 1 : 0;
}

// ---------------------------------------------------------------------------
// K0: materialize all 31 float inputs as fp32 into contiguous ws region.
// ---------------------------------------------------------------------------
struct P31 { const void* p[31]; };

__global__ __launch_bounds__(256) void k_convert(P31 a, const int* __restrict__ flag,
                                                 float* __restrict__ cw){
    const int fp32 = *flag;
    const int i = blockIdx.x * 256 + threadIdx.x;
    if (i >= TOTW) return;
    const int offs[32] = {
        0, 512064, 515392, 516068, 516120, 519448, 520124, 520176, 520852,
        520878, 521554, 521580, 521996, 522012, 522524, 522556, 523388,
        523414, 523830, 523846, 524358, 524390, 525222, 525248, 525300,
        525976, 526028, 526080, 526756, 526808, 734808, TOTW };
    int seg = 0;
    while (i >= offs[seg + 1]) ++seg;
    const int k = i - offs[seg];
    cw[i] = fp32 ? ((const float*)a.p[seg])[k] : bfu(((const u16*)a.p[seg])[k]);
}

// ---------------------------------------------------------------------------
// K1: proj[dir][t][g] = sum_k emb[t,k] * Wih_dir[g,k]
// ---------------------------------------------------------------------------
__global__ __launch_bounds__(128) void k_proj(const float* __restrict__ emb,
                                              const float* __restrict__ WihF,
                                              const float* __restrict__ WihB,
                                              float* __restrict__ projF,
                                              float* __restrict__ projB){
    __shared__ float x[IN_];
    const int t = blockIdx.x;
    const int tid = threadIdx.x;
    if (tid < IN_) x[tid] = emb[t * IN_ + tid];
    __syncthreads();
    if (tid < 2 * G_){
        const int dir = tid / G_;
        const int g   = tid - dir * G_;
        const float* w = (dir ? WihB : WihF) + g * IN_;
        float acc = 0.f;
        #pragma unroll
        for (int i = 0; i < IN_; ++i) acc += x[i] * w[i];
        (dir ? projB : projF)[t * G_ + g] = acc;
    }
}

// ---------------------------------------------------------------------------
// K2: biLSTM encoder. 1 block/node; wave0 = fwd, wave1 = bwd. Lane g (<52)
// owns one gate; h broadcast via shfl; next proj row prefetched.
// ---------------------------------------------------------------------------
__global__ __launch_bounds__(128) void k_lstm(const int* __restrict__ toks_g,
        const float* __restrict__ projF, const float* __restrict__ projB,
        const float* __restrict__ WhhF, const float* __restrict__ bF,
        const float* __restrict__ WhhB, const float* __restrict__ bB,
        const float* __restrict__ Wp1, const float* __restrict__ bp1,
        const float* __restrict__ Wp2, const float* __restrict__ bp2,
        float* __restrict__ state_h, float* __restrict__ state_c){
    __shared__ int   toks[L_];
    __shared__ float hcat[TWOH];
    __shared__ float ccat[TWOH];
    const int n = blockIdx.x, tid = threadIdx.x;
    const int wave = tid >> 6, lane = tid & 63;
    if (tid < L_) toks[tid] = toks_g[n * L_ + tid];

    const float* proj = wave ? projB : projF;
    const float* Whh  = wave ? WhhB : WhhF;
    const float* bp   = wave ? bB   : bF;

    float wh[H_];
    #pragma unroll
    for (int j = 0; j < H_; ++j) wh[j] = 0.f;
    float bb = 0.f;
    if (lane < G_){
        bb = bp[lane];
        #pragma unroll
        for (int j = 0; j < H_; ++j) wh[j] = Whh[lane * H_ + j];
    }
    __syncthreads();

    float h = 0.f, c = 0.f;
    int tok0 = wave ? toks[L_ - 1] : toks[0];
    float gpre = (lane < G_) ? proj[tok0 * G_ + lane] : 0.f;

    for (int t = 0; t < L_; ++t){
        float gv = gpre + bb;
        if (t + 1 < L_){
            int tn = wave ? toks[L_ - 2 - t] : toks[t + 1];
            gpre = (lane < G_) ? proj[tn * G_ + lane] : 0.f;   // prefetch
        }
        #pragma unroll
        for (int j = 0; j < H_; ++j) gv += __shfl(h, j, 64) * wh[j];
        float iv = __shfl(gv, lane,      64);
        float fv = __shfl(gv, lane + 13, 64);
        float gg = __shfl(gv, lane + 26, 64);
        float ov = __shfl(gv, lane + 39, 64);
        c = sigf(fv) * c + sigf(iv) * tanh_(gg);
        h = sigf(ov) * tanh_(c);
    }

    if (lane < H_){ hcat[wave * H_ + lane] = h; ccat[wave * H_ + lane] = c; }
    __syncthreads();

    if (lane < TWOH){
        if (wave == 0){
            float a = bp1[lane];
            #pragma unroll
            for (int k = 0; k < TWOH; ++k) a += hcat[k] * Wp1[lane * TWOH + k];
            state_h[n * TWOH + lane] = a;
        } else {
            float a = bp2[lane];
            #pragma unroll
            for (int k = 0; k < TWOH; ++k) a += ccat[k] * Wp2[lane * TWOH + k];
            state_c[n * TWOH + lane] = a;
        }
    }
}

// ---------------------------------------------------------------------------
// K3: two-layer GCN + final linear; one block per path (0 = h, 1 = c).
// ---------------------------------------------------------------------------
__global__ __launch_bounds__(256) void k_gcn(const int* __restrict__ eidx,
        const float* __restrict__ state_h, const float* __restrict__ state_c,
        const float* gh_W1, const float* gh_b1, const float* gh_W2, const float* gh_b2,
        const float* gh_Wf, const float* gh_bf,
        const float* gc_W1, const float* gc_b1, const float* gc_W2, const float* gc_b2,
        const float* gc_Wf, const float* gc_bf,
        float* __restrict__ sh, float* __restrict__ sc){
    __shared__ float xs[N_][33];
    __shared__ float dinv[N_];
    __shared__ float xw[N_][32];
    __shared__ float acc[N_][32];
    const int tid = threadIdx.x;
    const int p = blockIdx.x;
    const float* xin = p ? state_c : state_h;
    const float* W1  = p ? gc_W1 : gh_W1;  const float* b1  = p ? gc_b1 : gh_b1;
    const float* W2  = p ? gc_W2 : gh_W2;  const float* b2  = p ? gc_b2 : gh_b2;
    const float* Wf  = p ? gc_Wf : gh_Wf;  const float* bfp = p ? gc_bf : gh_bf;
    float* outp = p ? sc : sh;

    for (int i = tid; i < N_ * TWOH; i += 256) xs[i / TWOH][i % TWOH] = xin[i];
    for (int i = tid; i < N_; i += 256) dinv[i] = 1.0f;   // self loop
    __syncthreads();
    for (int e = tid; e < E_; e += 256) atomicAdd(&dinv[eidx[E_ + e]], 1.0f);
    __syncthreads();
    for (int i = tid; i < N_; i += 256) dinv[i] = rsqrtf(dinv[i]);
    __syncthreads();

    // layer 1: 26 -> 16
    for (int i = tid; i < N_ * 16; i += 256){
        int nn = i >> 4, f = i & 15;
        float a = 0.f;
        #pragma unroll
        for (int k = 0; k < TWOH; ++k) a += xs[nn][k] * W1[k * 16 + f];
        xw[nn][f] = a;
    }
    __syncthreads();
    for (int i = tid; i < N_ * 16; i += 256){ int nn = i >> 4, f = i & 15; acc[nn][f] = dinv[nn] * dinv[nn] * xw[nn][f]; }
    __syncthreads();
    for (int e = tid; e < E_; e += 256){
        int s = eidx[e], d = eidx[E_ + e];
        float nm = dinv[s] * dinv[d];
        #pragma unroll
        for (int f = 0; f < 16; ++f) atomicAdd(&acc[d][f], nm * xw[s][f]);
    }
    __syncthreads();
    for (int i = tid; i < N_ * 16; i += 256){
        int nn = i >> 4, f = i & 15;
        float a = acc[nn][f] + b1[f];
        xs[nn][f] = a > 0.f ? a : 0.01f * a;
    }
    __syncthreads();

    // layer 2: 16 -> 32
    for (int i = tid; i < N_ * 32; i += 256){
        int nn = i >> 5, f = i & 31;
        float a = 0.f;
        #pragma unroll
        for (int k = 0; k < 16; ++k) a += xs[nn][k] * W2[k * 32 + f];
        xw[nn][f] = a;
    }
    __syncthreads();
    for (int i = tid; i < N_ * 32; i += 256){ int nn = i >> 5, f = i & 31; acc[nn][f] = dinv[nn] * dinv[nn] * xw[nn][f]; }
    __syncthreads();
    for (int e = tid; e < E_; e += 256){
        int s = eidx[e], d = eidx[E_ + e];
        float nm = dinv[s] * dinv[d];
        #pragma unroll
        for (int f = 0; f < 32; ++f) atomicAdd(&acc[d][f], nm * xw[s][f]);
    }
    __syncthreads();
    for (int i = tid; i < N_ * 32; i += 256){
        int nn = i >> 5, f = i & 31;
        float a = acc[nn][f] + b2[f];
        xs[nn][f] = a > 0.f ? a : 0.01f * a;
    }
    __syncthreads();

    // final linear: 32 -> 26
    for (int i = tid; i < N_ * TWOH; i += 256){
        int nn = i / TWOH, d = i % TWOH;
        float a = bfp[d];
        #pragma unroll
        for (int k = 0; k < 32; ++k) a += xs[nn][k] * Wf[k * TWOH + d];
        outp[i] = a;
    }
}

// ---------------------------------------------------------------------------
// K4: decoder rows. One thread per (n,l). l>0: h0=c0=0 (scalar gates only).
// ---------------------------------------------------------------------------
__global__ __launch_bounds__(256) void k_dec(const int* __restrict__ toks,
        const float* __restrict__ sh, const float* __restrict__ sc,
        const float* WihF, const float* WhhF, const float* bF,
        const float* WihB, const float* WhhB, const float* bB,
        float* __restrict__ dec){
    __shared__ float wih[2][G_], bias[2][G_], whh[2][G_][H_];
    const int tid = threadIdx.x;
    for (int i = tid; i < 2 * G_; i += 256){
        int d = i / G_, k = i % G_;
        wih[d][k]  = (d ? WihB : WihF)[k];
        bias[d][k] = (d ? bB : bF)[k];
    }
    for (int i = tid; i < 2 * G_ * H_; i += 256){
        int d = i / (G_ * H_), rr = i % (G_ * H_), k = rr / H_, j = rr % H_;
        whh[d][k][j] = (d ? WhhB : WhhF)[k * H_ + j];
    }
    __syncthreads();

    const int r = blockIdx.x * 256 + tid;
    const int n = r >> 7, l = r & 127;
    const bool first = (l == 0);
    const float prev = first ? -1.0f : (float)toks[n * L_ + l - 1];

    for (int d = 0; d < 2; ++d){
        float h0[H_], c0[H_];
        #pragma unroll
        for (int j = 0; j < H_; ++j){
            h0[j] = first ? sh[n * TWOH + d * H_ + j] : 0.f;
            c0[j] = first ? sc[n * TWOH + d * H_ + j] : 0.f;
        }
        #pragma unroll
        for (int j = 0; j < H_; ++j){
            float gi = prev * wih[d][j]      + bias[d][j];
            float gf = prev * wih[d][13 + j] + bias[d][13 + j];
            float gg = prev * wih[d][26 + j] + bias[d][26 + j];
            float go = prev * wih[d][39 + j] + bias[d][39 + j];
            if (first){
                #pragma unroll
                for (int k = 0; k < H_; ++k){
                    float hk = h0[k];
                    gi += hk * whh[d][j][k];
                    gf += hk * whh[d][13 + j][k];
                    gg += hk * whh[d][26 + j][k];
                    go += hk * whh[d][39 + j][k];
                }
            }
            float cc = sigf(gf) * c0[j] + sigf(gi) * tanh_(gg);
            float hh = sigf(go) * tanh_(cc);
            dec[(size_t)r * TWOH + d * H_ + j] = hh;
        }
    }
}

// ---------------------------------------------------------------------------
// K5: out[r][v] = dec[r][:] . Wout[v][:] + bout[v], fp32 stores (float2/thread).
// ---------------------------------------------------------------------------
#define RT 64
#define VT 512
__global__ __launch_bounds__(256) void k_out(const float* __restrict__ dec,
        const float* __restrict__ Wout, const float* __restrict__ bout,
        float* __restrict__ out){
    __shared__ float dl[RT * 28];      // dec tile, rows padded to 28
    __shared__ float wl[VT * 26];      // Wout tile fp32 (53248 B)
    const int tid = threadIdx.x;
    const int r0 = blockIdx.x * RT;
    const int v0 = blockIdx.y * VT;
    const int nv = min(VT, V_ - v0);

    for (int i = tid; i < RT * 28; i += 256){
        int rr = i / 28, k = i % 28;
        dl[i] = (k < TWOH) ? dec[(size_t)(r0 + rr) * TWOH + k] : 0.f;
    }
    {   // rows v0..v0+nv contiguous: nv*26 floats, nv even -> /4 exact? nv*26/4: nv=512 -> 3328 ok; nv=320 -> 2080 ok
        const float4* src = (const float4*)(Wout + (size_t)v0 * TWOH);
        float4* dst = (float4*)wl;
        const int n4 = nv * TWOH / 4;
        for (int i = tid; i < n4; i += 256) dst[i] = src[i];
    }
    __syncthreads();

    const int lv = 2 * tid;
    if (lv < nv){
        float wa[28], wb[28];
        #pragma unroll
        for (int k = 0; k < TWOH; ++k){ wa[k] = wl[lv * TWOH + k]; wb[k] = wl[(lv + 1) * TWOH + k]; }
        wa[26] = wa[27] = wb[26] = wb[27] = 0.f;
        const int v = v0 + lv;
        const float ba = bout[v], bb2 = bout[v + 1];
        float2* outp = (float2*)(out + (size_t)r0 * V_ + v);
        for (int rr = 0; rr < RT; ++rr){
            const float* dp = dl + rr * 28;
            float sA = ba, sB = bb2;
            #pragma unroll
            for (int k = 0; k < 28; ++k){ float dk = dp[k]; sA += dk * wa[k]; sB += dk * wb[k]; }
            outp[(size_t)rr * (V_ / 2)] = make_float2(sA, sB);
        }
    }
}

// ---------------------------------------------------------------------------
extern "C" void kernel_launch(void* const* d_in, const int* in_sizes, int n_in,
                              void* d_out, int out_size, void* d_ws, size_t ws_size,
                              hipStream_t stream){
    // ws layout (floats)
    int*   flag  = (int*)d_ws;
    float* cw    = (float*)d_ws + 64;          // converted weights: TOTW floats
    float* projF = cw + TOTW;                   // 8000*52
    float* projB = projF + 416000;
    float* state_h = projB + 416000;            // 128*26 each
    float* state_c = state_h + 3328;
    float* sh      = state_c + 3328;
    float* sc      = sh + 3328;
    float* dec     = sc + 3328;                 // 16384*26

    float* cEmb   = cw + 0;
    float* cWihF  = cw + 512064;
    float* cWhhF  = cw + 515392;
    float* cbF    = cw + 516068;
    float* cWihB  = cw + 516120;
    float* cWhhB  = cw + 519448;
    float* cbB    = cw + 520124;
    float* cWp1   = cw + 520176;
    float* cbp1   = cw + 520852;
    float* cWp2   = cw + 520878;
    float* cbp2   = cw + 521554;
    float* cghW1  = cw + 521580;
    float* cghb1  = cw + 521996;
    float* cghW2  = cw + 522012;
    float* cghb2  = cw + 522524;
    float* cghWf  = cw + 522556;
    float* cghbf  = cw + 523388;
    float* cgcW1  = cw + 523414;
    float* cgcb1  = cw + 523830;
    float* cgcW2  = cw + 523846;
    float* cgcb2  = cw + 524358;
    float* cgcWf  = cw + 524390;
    float* cgcbf  = cw + 525222;
    float* cWihFd = cw + 525248;
    float* cWhhFd = cw + 525300;
    float* cbFd   = cw + 525976;
    float* cWihBd = cw + 526028;
    float* cWhhBd = cw + 526080;
    float* cbBd   = cw + 526756;
    float* cWout  = cw + 526808;
    float* cbout  = cw + 734808;

    const int* x_tokens   = (const int*)d_in[0];
    const int* edge_index = (const int*)d_in[1];

    P31 a;
    for (int j = 0; j < 31; ++j) a.p[j] = d_in[2 + j];

    k_detect<<<1, 64, 0, stream>>>((const u16*)d_in[2], flag);
    k_convert<<<(TOTW + 255) / 256, 256, 0, stream>>>(a, flag, cw);
    k_proj<<<V_, 128, 0, stream>>>(cEmb, cWihF, cWihB, projF, projB);
    k_lstm<<<N_, 128, 0, stream>>>(x_tokens, projF, projB,
                                   cWhhF, cbF, cWhhB, cbB,
                                   cWp1, cbp1, cWp2, cbp2, state_h, state_c);
    k_gcn<<<2, 256, 0, stream>>>(edge_index, state_h, state_c,
                                 cghW1, cghb1, cghW2, cghb2, cghWf, cghbf,
                                 cgcW1, cgcb1, cgcW2, cgcb2, cgcWf, cgcbf,
                                 sh, sc);
    k_dec<<<(N_ * L_) / 256, 256, 0, stream>>>(x_tokens, sh, sc,
                                               cWihFd, cWhhFd, cbFd,
                                               cWihBd, cWhhBd, cbBd, dec);
    k_out<<<dim3((N_ * L_) / RT, (V_ + VT - 1) / VT), 256, 0, stream>>>(dec, cWout, cbout, (float*)d_out);
}